// Round 10
// baseline (186.280 us; speedup 1.0000x reference)
//
#include <hip/hip_runtime.h>
#include <stdint.h>

// Problem constants (match reference)
#define N_PRIORS 2097152
#define KTOP 512
#define NBINS 2048
#define NBLK 256                 // blocks for every kernel
#define SCAP 16                  // stash slots per k1 block (lambda=3.1, P(>16)~3e-7)
#define DCAP 4096                // = NBLK*SCAP, dense candidate capacity
#define SSTASH 0.9915f           // exact stash threshold; expected ~800 >= 512 (10 sigma)
#define DPRE 4.75f               // ln(T/(1-T))=4.759; d>4.75 is a strict superset of s>T

// ws layout (bytes):
//   0:     u32 blk_cnt[256]     1 KB
//   1024:  u64 stash[256*16]    32 KB   ends 33792   (zero-filled empties)
//   33792: float4 gbbox[512]    8 KB    ends 41984
//   41984: float garea[512]     2 KB    ends 44032
//   44032: float gscore[512]    2 KB    ends 46080
//   46080: u64 supW[512*8]      32 KB   ends 78848
//   78848: u32 gmeta[4] {nf, done}

__device__ __forceinline__ uint64_t pack_key(float s, int idx) {
    // descending score, ascending index tie-break (== stable top_k)
    return ((uint64_t)__float_as_uint(s) << 32) | (uint32_t)(~idx);
}

__device__ __forceinline__ float score_of(float c0, float c1) {
    #pragma clang fp contract(off)
    float m  = fmaxf(c0, c1);
    float e0 = expf(c0 - m);
    float e1 = expf(c1 - m);
    return e1 / (e0 + e1);
}

__device__ __forceinline__ int bin_of(float s) {
    #pragma clang fp contract(off)
    int b = (int)((s - 0.9f) * 20480.0f);
    return b > (NBINS - 1) ? (NBINS - 1) : b;
}

// decode one candidate (exact numpy op order) and store at rank slot
__device__ __forceinline__ void decode_to(uint64_t key, const float4* loc,
                                          const float4* priors, float4* gbbox,
                                          float* garea, float* gscore, int slot) {
    #pragma clang fp contract(off)
    float sc = __uint_as_float((uint32_t)(key >> 32));
    int idx  = (int)(~(uint32_t)key);
    float4 l = loc[idx];
    float4 p = priors[idx];
    float cx = p.x + (l.x * 0.1f) * p.z;
    float cy = p.y + (l.y * 0.1f) * p.w;
    float w  = p.z * expf(l.z * 0.2f);
    float h  = p.w * expf(l.w * 0.2f);
    float x1 = cx - w * 0.5f;
    float y1 = cy - h * 0.5f;
    float x2 = x1 + w;
    float y2 = y1 + h;
    x1 *= 2048.0f; y1 *= 2048.0f; x2 *= 2048.0f; y2 *= 2048.0f;
    gbbox[slot]  = make_float4(x1, y1, x2, y2);
    garea[slot]  = (x2 - x1 + 1.0f) * (y2 - y1 + 1.0f);
    gscore[slot] = sc;
}

// K1: stream conf; cheap d-filter, exact score for rare survivors; fixed stash.
__launch_bounds__(1024)
__global__ void k1_stash(const float4* __restrict__ conf4,
                         uint32_t* __restrict__ blk_cnt,
                         uint64_t* __restrict__ stash) {
    #pragma clang fp contract(off)
    __shared__ uint64_t stage[SCAP];
    __shared__ uint32_t lcnt;
    int tid = threadIdx.x, blk = blockIdx.x;
    if (tid == 0) lcnt = 0u;
    if (tid < SCAP) stage[tid] = 0ull;
    __syncthreads();
    #pragma unroll
    for (int i = 0; i < 4; ++i) {
        int f4i = blk * 4096 + i * 1024 + tid;
        float4 c = conf4[f4i];
        // d-filter: s=sigmoid(c1-c0); s>SSTASH => d>4.759 > DPRE (superset, exact)
        if (c.y - c.x > DPRE) {
            float s = score_of(c.x, c.y);
            if (s > SSTASH) {
                uint32_t p = atomicAdd(&lcnt, 1u);
                if (p < SCAP) stage[p] = pack_key(s, 2 * f4i);
            }
        }
        if (c.w - c.z > DPRE) {
            float s = score_of(c.z, c.w);
            if (s > SSTASH) {
                uint32_t p = atomicAdd(&lcnt, 1u);
                if (p < SCAP) stage[p] = pack_key(s, 2 * f4i + 1);
            }
        }
    }
    __syncthreads();
    if (tid < SCAP) stash[blk * SCAP + tid] = stage[tid];
    if (tid == 0) blk_cnt[blk] = lcnt;
}

// K2: compact stash -> LDS, rank each candidate (wave-per-cand), decode top-512.
__launch_bounds__(1024)
__global__ void k2_rank(const float4* __restrict__ loc,
                        const float4* __restrict__ priors,
                        const float4* __restrict__ conf4,
                        const uint32_t* __restrict__ blk_cnt,
                        const uint64_t* __restrict__ stash,
                        float4* __restrict__ gbbox,
                        float* __restrict__ garea,
                        float* __restrict__ gscore,
                        uint32_t* __restrict__ gmeta) {
    #pragma clang fp contract(off)
    __shared__ uint64_t dense[DCAP];        // 32 KB
    __shared__ uint32_t hist[NBINS];        // 8 KB (fallback only)
    __shared__ uint32_t wvtot[16], wvbase[16];
    __shared__ uint32_t nrawS, fbS, nTotS, scntS;
    __shared__ int bmaxS;
    int tid = threadIdx.x, blk = blockIdx.x;
    int lane = tid & 63, wv = tid >> 6;

    if (tid == 0) { nrawS = 0u; fbS = 0u; scntS = 0u; bmaxS = 0; }
    __syncthreads();
    if (tid < NBLK) {
        uint32_t c = blk_cnt[tid];
        if (c > SCAP) atomicOr(&fbS, 1u);
        atomicAdd(&nrawS, c < SCAP ? c : SCAP);
    }
    __syncthreads();
    bool fb = (fbS != 0u) || (nrawS < KTOP);

    if (!fb) {
        // ---- load full stash coalesced; two-level prefix compaction ----
        uint64_t v0 = stash[tid], v1 = stash[tid + 1024];
        uint64_t v2 = stash[tid + 2048], v3 = stash[tid + 3072];
        uint32_t lc = (v0 != 0ull) + (v1 != 0ull) + (v2 != 0ull) + (v3 != 0ull);
        uint32_t incl = lc;
        #pragma unroll
        for (int m = 1; m < 64; m <<= 1) {
            uint32_t o = __shfl_up(incl, m);
            if (lane >= m) incl += o;
        }
        uint32_t excl = incl - lc;
        if (lane == 63) wvtot[wv] = incl;
        __syncthreads();
        if (wv == 0) {
            uint32_t t = (lane < 16) ? wvtot[lane] : 0u;
            uint32_t ti = t;
            #pragma unroll
            for (int m = 1; m < 16; m <<= 1) {
                uint32_t o = __shfl_up(ti, m);
                if (lane >= m) ti += o;
            }
            if (lane < 16) wvbase[lane] = ti - t;
            if (lane == 15) nTotS = ti;
        }
        __syncthreads();
        uint32_t pos = wvbase[wv] + excl;
        if (v0) dense[pos++] = v0;
        if (v1) dense[pos++] = v1;
        if (v2) dense[pos++] = v2;
        if (v3) dense[pos++] = v3;
        __syncthreads();
        uint32_t n = nTotS;                 // == nrawS (no overflow on this path)

        // ---- rank: wave per candidate; lane 0 decodes if rank < 512 ----
        int cidx = blk * 16 + wv;           // 256 blocks x 16 waves covers DCAP
        if ((uint32_t)cidx < n) {
            uint64_t K = dense[cidx];
            int cnt = 0;
            for (uint32_t j = lane; j < n; j += 64) cnt += (dense[j] > K) ? 1 : 0;
            #pragma unroll
            for (int m = 1; m < 64; m <<= 1) cnt += __shfl_xor(cnt, m);
            if (lane == 0 && cnt < KTOP)
                decode_to(K, loc, priors, gbbox, garea, gscore, cnt);
        }
        if (blk == 0 && tid == 0) { gmeta[0] = KTOP; gmeta[1] = 0u; }
        return;
    }

    // ---------- exact fallback (cold, never taken): block 0 solo ----------
    if (blk != 0) return;
    if (tid < KTOP) {
        gbbox[tid] = make_float4(0.f, 0.f, 0.f, 0.f);
        garea[tid] = 1.f; gscore[tid] = 0.f;
    }
    for (int b = tid; b < NBINS; b += 1024) hist[b] = 0u;
    __syncthreads();
    for (int f = tid; f < N_PRIORS / 2; f += 1024) {
        float4 c = conf4[f];
        float s0 = score_of(c.x, c.y);
        float s1 = score_of(c.z, c.w);
        if (s0 > 0.9f) atomicAdd(&hist[bin_of(s0)], 1u);
        if (s1 > 0.9f) atomicAdd(&hist[bin_of(s1)], 1u);
    }
    __syncthreads();
    for (int off = 1; off < NBINS; off <<= 1) {
        int b0 = tid, b1 = tid + 1024;
        uint32_t x0 = hist[b0] + ((b0 + off < NBINS) ? hist[b0 + off] : 0u);
        uint32_t x1 = hist[b1] + ((b1 + off < NBINS) ? hist[b1 + off] : 0u);
        __syncthreads();
        hist[b0] = x0; hist[b1] = x1;
        __syncthreads();
    }
    if (hist[tid] >= KTOP) atomicMax(&bmaxS, tid);
    if (hist[tid + 1024] >= KTOP) atomicMax(&bmaxS, tid + 1024);
    __syncthreads();
    int B = bmaxS;
    for (int f = tid; f < N_PRIORS / 2; f += 1024) {
        float4 c = conf4[f];
        float s0 = score_of(c.x, c.y);
        float s1 = score_of(c.z, c.w);
        if (s0 > 0.9f && bin_of(s0) >= B) {
            uint32_t p = atomicAdd(&scntS, 1u);
            if (p < DCAP) dense[p] = pack_key(s0, 2 * f);
        }
        if (s1 > 0.9f && bin_of(s1) >= B) {
            uint32_t p = atomicAdd(&scntS, 1u);
            if (p < DCAP) dense[p] = pack_key(s1, 2 * f + 1);
        }
    }
    __syncthreads();
    uint32_t m = scntS < DCAP ? scntS : DCAP;
    for (uint32_t c = wv; c < m; c += 16) {
        uint64_t K = dense[c];
        int cnt = 0;
        for (uint32_t j = lane; j < m; j += 64) cnt += (dense[j] > K) ? 1 : 0;
        #pragma unroll
        for (int mm = 1; mm < 64; mm <<= 1) cnt += __shfl_xor(cnt, mm);
        if (lane == 0 && cnt < KTOP)
            decode_to(K, loc, priors, gbbox, garea, gscore, cnt);
    }
    __syncthreads();
    if (tid == 0) { gmeta[0] = m < KTOP ? m : KTOP; gmeta[1] = 0u; }
}

// K3: 2 suppression rows per block; last-finished block runs scan + epilogue.
__launch_bounds__(1024)
__global__ void k3_matrix(const float4* __restrict__ gbbox,
                          const float* __restrict__ garea,
                          const float* __restrict__ gscore,
                          uint64_t* __restrict__ supW,
                          uint32_t* __restrict__ gmeta,
                          float* __restrict__ out) {
    #pragma clang fp contract(off)
    __shared__ uint64_t supLDS[DCAP];       // 32 KB (tail only)
    __shared__ float4 bpk[KTOP];            // 8 KB
    __shared__ float  sar[KTOP];            // 2 KB
    __shared__ uint64_t rowany8[8], keepw[8];
    __shared__ int amLast;
    int tid = threadIdx.x, blk = blockIdx.x;
    int lane = tid & 63, wv = tid >> 6;

    if (tid < KTOP) { bpk[tid] = gbbox[tid]; sar[tid] = garea[tid]; }
    __syncthreads();
    {
        int r   = 2 * blk + (tid >> 9);
        int col = tid & 511;
        float4 rb = bpk[r];  float ra = sar[r];
        float4 cb = bpk[col];
        float xx1 = fmaxf(rb.x, cb.x);
        float yy1 = fmaxf(rb.y, cb.y);
        float xx2 = fminf(rb.z, cb.z);
        float yy2 = fminf(rb.w, cb.w);
        float ww = fmaxf(xx2 - xx1 + 1.0f, 0.0f);
        float hh = fmaxf(yy2 - yy1 + 1.0f, 0.0f);
        float inter = ww * hh;
        float iou = inter / (ra + sar[col] - inter);
        uint64_t word = __ballot(iou > 0.4f && col > r);
        if (lane == 0) supW[r * 8 + ((tid >> 6) & 7)] = word;
    }
    __threadfence();                        // release this block's supW rows
    __syncthreads();
    if (tid == 0) amLast = (atomicAdd(&gmeta[1], 1u) == (uint32_t)(NBLK - 1));
    __syncthreads();
    if (!amLast) return;
    __threadfence();                        // acquire: see all blocks' supW

    uint32_t nf = gmeta[0];
    for (int t = tid; t < DCAP; t += 1024) supLDS[t] = supW[t];
    __syncthreads();
    if (tid < KTOP) {                       // waves 0..7: rowany bits
        uint64_t a = 0ull;
        #pragma unroll
        for (int k = 0; k < 8; ++k) a |= supLDS[tid * 8 + k];
        uint64_t bal = __ballot(a != 0ull);
        if (lane == 0) rowany8[wv] = bal;
    }
    __syncthreads();

    if (tid == 0) {
        #define VAL64(c) ((nf >= (uint32_t)(((c)+1)*64)) ? ~0ull : \
            ((nf > (uint32_t)((c)*64)) ? ((1ull << (nf - (c)*64)) - 1ull) : 0ull))
        uint64_t kp0 = VAL64(0), kp1 = VAL64(1), kp2 = VAL64(2), kp3 = VAL64(3);
        uint64_t kp4 = VAL64(4), kp5 = VAL64(5), kp6 = VAL64(6), kp7 = VAL64(7);
        #define APPLYROW(i) do { const uint64_t* rp = supLDS + (size_t)(i) * 8; \
            kp0 &= ~rp[0]; kp1 &= ~rp[1]; kp2 &= ~rp[2]; kp3 &= ~rp[3]; \
            kp4 &= ~rp[4]; kp5 &= ~rp[5]; kp6 &= ~rp[6]; kp7 &= ~rp[7]; } while (0)
        #define CHUNK(c, KPC) do { uint64_t ra = rowany8[c]; uint64_t m = (KPC) & ra; \
            while (m) { int b = __builtin_ctzll(m); APPLYROW((c) * 64 + b); \
                uint64_t above = (b == 63) ? 0ull : (~0ull << (b + 1)); \
                m = (KPC) & ra & above; } } while (0)
        CHUNK(0, kp0); CHUNK(1, kp1); CHUNK(2, kp2); CHUNK(3, kp3);
        CHUNK(4, kp4); CHUNK(5, kp5); CHUNK(6, kp6); CHUNK(7, kp7);
        keepw[0] = kp0; keepw[1] = kp1; keepw[2] = kp2; keepw[3] = kp3;
        keepw[4] = kp4; keepw[5] = kp5; keepw[6] = kp6; keepw[7] = kp7;
        #undef CHUNK
        #undef APPLYROW
        #undef VAL64
    }
    __syncthreads();

    if (tid < KTOP) {
        const float inv = 1.0f / 2048.0f;   // exact pow2
        int kb = (int)((keepw[tid >> 6] >> (tid & 63)) & 1ull);
        float4 bb = bpk[tid];
        float* o = out + tid * 5;
        if (kb) {
            o[0] = bb.x * inv;
            o[1] = bb.y * inv;
            o[2] = bb.z * inv;
            o[3] = bb.w * inv;
            o[4] = gscore[tid];
        } else {
            o[0] = 0.f; o[1] = 0.f; o[2] = 0.f; o[3] = 0.f; o[4] = 0.f;
        }
    }
}

extern "C" void kernel_launch(void* const* d_in, const int* in_sizes, int n_in,
                              void* d_out, int out_size, void* d_ws, size_t ws_size,
                              hipStream_t stream) {
    const float4* loc4  = (const float4*)d_in[0];   // [1,N,4]
    const float4* conf4 = (const float4*)d_in[1];   // [1,N,2] as float4 pairs
    const float4* pri4  = (const float4*)d_in[2];   // [N,4]
    float* outp = (float*)d_out;                    // [512,5]

    uint8_t* ws = (uint8_t*)d_ws;
    uint32_t* blk_cnt = (uint32_t*)ws;              // 1 KB
    uint64_t* stash   = (uint64_t*)(ws + 1024);     // 32 KB
    float4*   gbbox   = (float4*)(ws + 33792);      // 8 KB
    float*    garea   = (float*)(ws + 41984);       // 2 KB
    float*    gscore  = (float*)(ws + 44032);       // 2 KB
    uint64_t* supW    = (uint64_t*)(ws + 46080);    // 32 KB
    uint32_t* gmeta   = (uint32_t*)(ws + 78848);    // 16 B

    // no memset: blk_cnt/stash fully written by k1; gmeta{nf,done} by k2.
    k1_stash<<<NBLK, 1024, 0, stream>>>(conf4, blk_cnt, stash);
    k2_rank<<<NBLK, 1024, 0, stream>>>(loc4, pri4, conf4, blk_cnt, stash,
                                       gbbox, garea, gscore, gmeta);
    k3_matrix<<<NBLK, 1024, 0, stream>>>(gbbox, garea, gscore, supW, gmeta, outp);
}